// Round 9
// baseline (44.205 us; speedup 1.0000x reference)
//
#include <hip/hip_runtime.h>

#define Nn 512
#define Dd 128
#define Kk 2048
#define Cc 100
#define NPAIR 8         // pairs per class; block handles kc = pair and pair+8
#define KCW 64          // stats granularity: 64 wave-chunks of 32 cols
#define G  8            // samples per pass
#define SQROW 164       // padded q-row stride in LDS floats
constexpr float INV_T = 1.0f / 0.07f;

// ws layout (floats):
// [0, 32768)        stats_m[n*KCW+kcw]
// [32768, 65536)    stats_s[n*KCW+kcw]
// [65536, 66048)    per-sample loss

__device__ __forceinline__ void load_V(float4* V, const float* gcol) {
    #pragma unroll
    for (int j = 0; j < 16; ++j)
        V[j] = *reinterpret_cast<const float4*>(gcol + (size_t)j * Kk);
}

__global__ __launch_bounds__(256) void chunk_kernel(
    const float* __restrict__ q,
    const float* __restrict__ queue, const int* __restrict__ labels,
    float* __restrict__ ws)
{
    const int c  = blockIdx.x >> 3;      // class
    const int pr = blockIdx.x & 7;       // pair -> items kc = pr, pr + 8
    const int t  = threadIdx.x;
    const int w  = t >> 6;               // wave 0..3 -> 32-col sub-chunk
    const int l  = t & 63;               // lane
    const int dg = l >> 3;               // d-group 0..7 (16 rows each)
    const int c4 = l & 7;                // col-group 0..7 (4 cols each)

    __shared__ int   s_list[Nn];
    __shared__ int   s_cnt;
    __shared__ float sq[G * SQROW];      // padded staged q rows, 5.25 KB

    // issue item-0's 16 loads first (overlaps the label scan below)
    const float* slabbase = queue + (size_t)c * Dd * Kk
                          + (size_t)(dg * 16) * Kk + w * 32 + c4 * 4;
    float4 V[16];
    load_V(V, slabbase + pr * 128);

    // wave-0 ballot scan: deterministic ordered sample list for class c
    if (t < 64) {
        int cnt = 0;
        for (int base = 0; base < Nn; base += 64) {
            int lab = labels[base + t];
            unsigned long long m = __ballot(lab == c);
            if (lab == c) {
                int pos = __popcll(m & ((1ull << t) - 1ull));
                s_list[cnt + pos] = base + t;
            }
            cnt += __popcll(m);
        }
        if (t == 0) s_cnt = cnt;
    }
    __syncthreads();
    const int cnt = s_cnt;
    if (cnt == 0) return;                 // block-uniform (rare)

    float* stats_m = ws;
    float* stats_s = ws + (size_t)Nn * KCW;

    #pragma unroll
    for (int item = 0; item < 2; ++item) {
        const int kc = pr + item * 8;
        if (item) load_V(V, slabbase + kc * 128);
        const int kcw = kc * 4 + w;

        for (int g0 = 0; g0 < cnt; g0 += G) {
            const int gs = min(G, cnt - g0);

            // stage q rows padded (idx(d) = d + 4*(d>>4)): 256 threads, one float4 each
            {
                const int s = t >> 5;    // sample 0..7
                const int f = t & 31;    // float4 chunk
                const int d = 4 * f;
                float4 v = make_float4(0.f, 0.f, 0.f, 0.f);
                if (s < gs)
                    v = *reinterpret_cast<const float4*>(q + (size_t)s_list[g0 + s] * Dd + d);
                *reinterpret_cast<float4*>(&sq[s * SQROW + d + 4 * (d >> 4)]) = v;
            }
            __syncthreads();

            #pragma unroll
            for (int s = 0; s < G; ++s) {
                if (s >= gs) break;      // block-uniform

                // 16 q-values for this dg-group: 4 bank-disjoint b128 broadcasts
                const float* srow = &sq[s * SQROW + 20 * dg];
                const float4 qa = *reinterpret_cast<const float4*>(srow + 0);
                const float4 qb = *reinterpret_cast<const float4*>(srow + 4);
                const float4 qc = *reinterpret_cast<const float4*>(srow + 8);
                const float4 qd = *reinterpret_cast<const float4*>(srow + 12);
                const float qq[16] = {qa.x, qa.y, qa.z, qa.w, qb.x, qb.y, qb.z, qb.w,
                                      qc.x, qc.y, qc.z, qc.w, qd.x, qd.y, qd.z, qd.w};

                float4 a = make_float4(0.f, 0.f, 0.f, 0.f);
                #pragma unroll
                for (int j = 0; j < 16; ++j) {
                    a.x = fmaf(qq[j], V[j].x, a.x);
                    a.y = fmaf(qq[j], V[j].y, a.y);
                    a.z = fmaf(qq[j], V[j].z, a.z);
                    a.w = fmaf(qq[j], V[j].w, a.w);
                }

                // d-reduce across dg (lane bits 3..5)
                #pragma unroll
                for (int mask = 8; mask <= 32; mask <<= 1) {
                    a.x += __shfl_xor(a.x, mask, 64);
                    a.y += __shfl_xor(a.y, mask, 64);
                    a.z += __shfl_xor(a.z, mask, 64);
                    a.w += __shfl_xor(a.w, mask, 64);
                }
                const float lx = a.x * INV_T, ly = a.y * INV_T;
                const float lz = a.z * INV_T, lw = a.w * INV_T;

                // softmax stats across c4 (lane bits 0..2)
                float mv = fmaxf(fmaxf(lx, ly), fmaxf(lz, lw));
                #pragma unroll
                for (int mask = 1; mask <= 4; mask <<= 1)
                    mv = fmaxf(mv, __shfl_xor(mv, mask, 64));
                float ev = expf(lx - mv) + expf(ly - mv) + expf(lz - mv) + expf(lw - mv);
                #pragma unroll
                for (int mask = 1; mask <= 4; mask <<= 1)
                    ev += __shfl_xor(ev, mask, 64);

                if (l == 0) {
                    const int n = s_list[g0 + s];
                    stats_m[(size_t)n * KCW + kcw] = mv;
                    stats_s[(size_t)n * KCW + kcw] = ev;
                }
            }
            __syncthreads();
        }
    }
}

__global__ __launch_bounds__(64) void loss_kernel(
    const float* __restrict__ q, const float* __restrict__ k,
    const float* __restrict__ ws, float* __restrict__ loss)
{
    const int n = blockIdx.x * 64 + threadIdx.x;
    const float* stats_m = ws;
    const float* stats_s = ws + (size_t)Nn * KCW;

    // l_pos = dot(q[n], k[n]) / T
    float lp = 0.f;
    const float4* qv = reinterpret_cast<const float4*>(q + (size_t)n * Dd);
    const float4* kv = reinterpret_cast<const float4*>(k + (size_t)n * Dd);
    #pragma unroll
    for (int j = 0; j < Dd / 4; ++j) {
        float4 a = qv[j], b = kv[j];
        lp = fmaf(a.x, b.x, lp); lp = fmaf(a.y, b.y, lp);
        lp = fmaf(a.z, b.z, lp); lp = fmaf(a.w, b.w, lp);
    }
    lp *= INV_T;

    const float4* mmv = reinterpret_cast<const float4*>(stats_m + (size_t)n * KCW);
    const float4* ssv = reinterpret_cast<const float4*>(stats_s + (size_t)n * KCW);

    float m = lp;
    #pragma unroll
    for (int j = 0; j < KCW / 4; ++j) {
        float4 a = mmv[j];
        m = fmaxf(m, fmaxf(fmaxf(a.x, a.y), fmaxf(a.z, a.w)));
    }
    float sum = expf(lp - m);
    #pragma unroll
    for (int j = 0; j < KCW / 4; ++j) {
        float4 a = mmv[j], b = ssv[j];
        sum += b.x * expf(a.x - m) + b.y * expf(a.y - m)
             + b.z * expf(a.z - m) + b.w * expf(a.w - m);
    }
    loss[n] = logf(sum) + m - lp;
}

__global__ __launch_bounds__(256) void reduce_kernel(
    const float* __restrict__ loss, float* __restrict__ out)
{
    __shared__ float red[256];
    const int t = threadIdx.x;
    red[t] = loss[t] + loss[t + 256];
    __syncthreads();
    for (int s = 128; s > 0; s >>= 1) {
        if (t < s) red[t] += red[t + s];
        __syncthreads();
    }
    if (t == 0) out[0] = red[0] / (float)Nn;
}

extern "C" void kernel_launch(void* const* d_in, const int* in_sizes, int n_in,
                              void* d_out, int out_size, void* d_ws, size_t ws_size,
                              hipStream_t stream) {
    const float* q      = (const float*)d_in[0];
    const float* k      = (const float*)d_in[1];
    const float* queue  = (const float*)d_in[2];
    // d_in[3] = class_weights — unused by the reference computation
    const int* labels   = (const int*)d_in[4];
    float* out          = (float*)d_out;
    float* ws           = (float*)d_ws;
    float* loss         = ws + 2 * (size_t)Nn * KCW;

    chunk_kernel<<<Cc * NPAIR, 256, 0, stream>>>(q, queue, labels, ws);
    loss_kernel<<<Nn / 64, 64, 0, stream>>>(q, k, ws, loss);
    reduce_kernel<<<1, 256, 0, stream>>>(loss, out);
}

// Round 10
// 38.061 us; speedup vs baseline: 1.1614x; 1.1614x over previous
//
#include <hip/hip_runtime.h>

#define Nn 512
#define Dd 128
#define Kk 2048
#define Cc 100
#define KC 16           // blocks per class; each block covers 128 cols
#define KCW 64          // stats granularity: 64 wave-chunks of 32 cols
#define G  8            // samples per pass
#define SQROW 164       // padded q-row stride in LDS floats
constexpr float INV_T = 1.0f / 0.07f;

// ws layout (floats):
// [0, 32768)        stats_m[n*KCW+kcw]
// [32768, 65536)    stats_s[n*KCW+kcw]
// [65536, 66048)    per-sample loss

__global__ __launch_bounds__(256) void chunk_kernel(
    const float* __restrict__ q,
    const float* __restrict__ queue, const int* __restrict__ labels,
    float* __restrict__ ws)
{
    const int c  = blockIdx.x >> 4;      // class
    const int kc = blockIdx.x & 15;      // 128-col block chunk
    const int t  = threadIdx.x;
    const int w  = t >> 6;               // wave 0..3 -> 32-col sub-chunk
    const int l  = t & 63;               // lane
    const int dg = l >> 3;               // d-group 0..7 (16 rows each)
    const int c4 = l & 7;                // col-group 0..7 (4 cols each)

    __shared__ int   s_list[Nn];
    __shared__ int   s_cnt;
    __shared__ float sq[G * SQROW];      // padded staged q rows, 5.25 KB

    // 1) prefetch all 8 label words FIRST (oldest in vmcnt queue ->
    //    ballot waits only on these, not on the V loads issued below)
    int lab[8];
    #pragma unroll
    for (int r = 0; r < 8; ++r) lab[r] = labels[l + r * 64];

    // 2) issue the 16 independent V loads (live across all passes)
    const float* gbase = queue + (size_t)c * Dd * Kk
                       + (size_t)(dg * 16) * Kk + kc * 128 + w * 32 + c4 * 4;
    float4 V[16];
    #pragma unroll
    for (int j = 0; j < 16; ++j)
        V[j] = *reinterpret_cast<const float4*>(gbase + (size_t)j * Kk);

    // 3) ballot scan from registers (wave 0): deterministic ordered sample list
    if (t < 64) {
        int cnt = 0;
        #pragma unroll
        for (int r = 0; r < 8; ++r) {
            unsigned long long m = __ballot(lab[r] == c);
            if (lab[r] == c) {
                int pos = __popcll(m & ((1ull << l) - 1ull));
                s_list[cnt + pos] = r * 64 + l;
            }
            cnt += __popcll(m);
        }
        if (l == 0) s_cnt = cnt;
    }
    __syncthreads();
    const int cnt = s_cnt;
    if (cnt == 0) return;                 // block-uniform (rare)

    float* stats_m = ws;
    float* stats_s = ws + (size_t)Nn * KCW;
    const int kcw = kc * 4 + w;

    for (int g0 = 0; g0 < cnt; g0 += G) {
        const int gs = min(G, cnt - g0);

        // stage q rows padded (idx(d) = d + 4*(d>>4)): 256 threads, one float4 each
        {
            const int s = t >> 5;        // sample 0..7
            const int f = t & 31;        // float4 chunk
            const int d = 4 * f;
            float4 v = make_float4(0.f, 0.f, 0.f, 0.f);
            if (s < gs)
                v = *reinterpret_cast<const float4*>(q + (size_t)s_list[g0 + s] * Dd + d);
            *reinterpret_cast<float4*>(&sq[s * SQROW + d + 4 * (d >> 4)]) = v;
        }
        __syncthreads();

        #pragma unroll
        for (int s = 0; s < G; ++s) {
            if (s >= gs) break;          // block-uniform

            // 16 q-values for this dg-group: 4 bank-disjoint b128 broadcasts
            const float* srow = &sq[s * SQROW + 20 * dg];
            const float4 qa = *reinterpret_cast<const float4*>(srow + 0);
            const float4 qb = *reinterpret_cast<const float4*>(srow + 4);
            const float4 qc = *reinterpret_cast<const float4*>(srow + 8);
            const float4 qd = *reinterpret_cast<const float4*>(srow + 12);
            const float qq[16] = {qa.x, qa.y, qa.z, qa.w, qb.x, qb.y, qb.z, qb.w,
                                  qc.x, qc.y, qc.z, qc.w, qd.x, qd.y, qd.z, qd.w};

            float4 a = make_float4(0.f, 0.f, 0.f, 0.f);
            #pragma unroll
            for (int j = 0; j < 16; ++j) {
                a.x = fmaf(qq[j], V[j].x, a.x);
                a.y = fmaf(qq[j], V[j].y, a.y);
                a.z = fmaf(qq[j], V[j].z, a.z);
                a.w = fmaf(qq[j], V[j].w, a.w);
            }

            // d-reduce across dg (lane bits 3..5)
            #pragma unroll
            for (int mask = 8; mask <= 32; mask <<= 1) {
                a.x += __shfl_xor(a.x, mask, 64);
                a.y += __shfl_xor(a.y, mask, 64);
                a.z += __shfl_xor(a.z, mask, 64);
                a.w += __shfl_xor(a.w, mask, 64);
            }
            const float lx = a.x * INV_T, ly = a.y * INV_T;
            const float lz = a.z * INV_T, lw = a.w * INV_T;

            // softmax stats across c4 (lane bits 0..2)
            float mv = fmaxf(fmaxf(lx, ly), fmaxf(lz, lw));
            #pragma unroll
            for (int mask = 1; mask <= 4; mask <<= 1)
                mv = fmaxf(mv, __shfl_xor(mv, mask, 64));
            float ev = expf(lx - mv) + expf(ly - mv) + expf(lz - mv) + expf(lw - mv);
            #pragma unroll
            for (int mask = 1; mask <= 4; mask <<= 1)
                ev += __shfl_xor(ev, mask, 64);

            if (l == 0) {
                const int n = s_list[g0 + s];
                stats_m[(size_t)n * KCW + kcw] = mv;
                stats_s[(size_t)n * KCW + kcw] = ev;
            }
        }
        __syncthreads();
    }
}

__global__ __launch_bounds__(64) void loss_kernel(
    const float* __restrict__ q, const float* __restrict__ k,
    const float* __restrict__ ws, float* __restrict__ loss)
{
    const int n = blockIdx.x * 64 + threadIdx.x;
    const float* stats_m = ws;
    const float* stats_s = ws + (size_t)Nn * KCW;

    // l_pos = dot(q[n], k[n]) / T
    float lp = 0.f;
    const float4* qv = reinterpret_cast<const float4*>(q + (size_t)n * Dd);
    const float4* kv = reinterpret_cast<const float4*>(k + (size_t)n * Dd);
    #pragma unroll
    for (int j = 0; j < Dd / 4; ++j) {
        float4 a = qv[j], b = kv[j];
        lp = fmaf(a.x, b.x, lp); lp = fmaf(a.y, b.y, lp);
        lp = fmaf(a.z, b.z, lp); lp = fmaf(a.w, b.w, lp);
    }
    lp *= INV_T;

    const float4* mmv = reinterpret_cast<const float4*>(stats_m + (size_t)n * KCW);
    const float4* ssv = reinterpret_cast<const float4*>(stats_s + (size_t)n * KCW);

    float m = lp;
    #pragma unroll
    for (int j = 0; j < KCW / 4; ++j) {
        float4 a = mmv[j];
        m = fmaxf(m, fmaxf(fmaxf(a.x, a.y), fmaxf(a.z, a.w)));
    }
    float sum = expf(lp - m);
    #pragma unroll
    for (int j = 0; j < KCW / 4; ++j) {
        float4 a = mmv[j], b = ssv[j];
        sum += b.x * expf(a.x - m) + b.y * expf(a.y - m)
             + b.z * expf(a.z - m) + b.w * expf(a.w - m);
    }
    loss[n] = logf(sum) + m - lp;
}

__global__ __launch_bounds__(256) void reduce_kernel(
    const float* __restrict__ loss, float* __restrict__ out)
{
    __shared__ float red[256];
    const int t = threadIdx.x;
    red[t] = loss[t] + loss[t + 256];
    __syncthreads();
    for (int s = 128; s > 0; s >>= 1) {
        if (t < s) red[t] += red[t + s];
        __syncthreads();
    }
    if (t == 0) out[0] = red[0] / (float)Nn;
}

extern "C" void kernel_launch(void* const* d_in, const int* in_sizes, int n_in,
                              void* d_out, int out_size, void* d_ws, size_t ws_size,
                              hipStream_t stream) {
    const float* q      = (const float*)d_in[0];
    const float* k      = (const float*)d_in[1];
    const float* queue  = (const float*)d_in[2];
    // d_in[3] = class_weights — unused by the reference computation
    const int* labels   = (const int*)d_in[4];
    float* out          = (float*)d_out;
    float* ws           = (float*)d_ws;
    float* loss         = ws + 2 * (size_t)Nn * KCW;

    chunk_kernel<<<Cc * KC, 256, 0, stream>>>(q, queue, labels, ws);
    loss_kernel<<<Nn / 64, 64, 0, stream>>>(q, k, ws, loss);
    reduce_kernel<<<1, 256, 0, stream>>>(loss, out);
}